// Round 8
// baseline (518.275 us; speedup 1.0000x reference)
//
#include <hip/hip_runtime.h>

#define D     4096   // row length
#define KKEEP 512    // entries to keep per row
#define TPB   256    // threads per block
#define NSEG  4      // float4 segments per thread (D/4/TPB)
#define NB    2048   // histogram bins (11-bit digits; round 2 uses low 1024 only)
#define BPT   (NB / TPB)             // 8 bins per thread in the scan
#define HA(d) ((d) + ((d) >> 3))     // padded hist address: chunk base = 9*tid
#define HWORDS (NB + NB / 8)         // 2304 words
#define RPB   8                      // rows per block (persistent, pipelined)

// Monotonic float -> uint key, 3 VALU ops (ashr, or, xor).
__device__ __forceinline__ unsigned key_of(float f) {
    unsigned u = __float_as_uint(f);
    return u ^ ((unsigned)((int)u >> 31) | 0x80000000u);
}
// Exact inverse of key_of.
__device__ __forceinline__ float val_of(unsigned k) {
    unsigned u = (k & 0x80000000u) ? (k ^ 0x80000000u) : ~k;
    return __uint_as_float(u);
}

// LDS-only barrier: drains DS ops (lgkmcnt) then raw s_barrier. Unlike
// __syncthreads(), does NOT wait vmcnt(0) -- global prefetch loads and emit
// stores stay in flight across the select. This is what lets row i+1's HBM
// read overlap row i's select (the phase-lock convoy was adding them: ~3200
// cyc memory + ~1900 cyc select per block = measured ~136 us vs ~85 floor).
// All LDS producer->consumer pairs are still lgkmcnt-drained + barriered.
__device__ __forceinline__ void bar_lds() {
    asm volatile("s_waitcnt lgkmcnt(0)" ::: "memory");
    __builtin_amdgcn_s_barrier();
    asm volatile("" ::: "memory");
}

__global__ __launch_bounds__(TPB, 7)
void topk_keep_kernel(const float* __restrict__ x, float* __restrict__ out) {
    const int tid = threadIdx.x;
    const unsigned lane = tid & 63u, wid = (unsigned)tid >> 6;
    const long row0 = (long)blockIdx.x * RPB;
    const float4* px = (const float4*)(x + row0 * D);
    float4*       po = (float4*)(out + row0 * D);

    __shared__ unsigned hist[HWORDS];
    __shared__ unsigned s_wtot[4];    // per-wave chunk totals (select scan)
    __shared__ unsigned s_sel[3];     // [selected digit, new remaining, bin count]
    __shared__ unsigned s_w01[4];     // tie slow path: packed seg0|seg1 totals
    __shared__ unsigned s_w23[4];     // tie slow path: packed seg2|seg3 totals

    // Zero once (incl. pad words 9t+8, never touched by atomics). Each round's
    // scan re-zeros its bins for the next round / next row.
    #pragma unroll
    for (int i = 0; i < 9; ++i) hist[tid + i * TPB] = 0;

    // First-row loads overlap the zeroing; bar_lds leaves them in flight.
    float4 f0 = px[tid], f1 = px[tid + TPB], f2 = px[tid + 2 * TPB], f3 = px[tid + 3 * TPB];
    bar_lds();

    #pragma unroll 1
    for (int row = 0; row < RPB; ++row) {
        // ---- Keys of current row (consumes f0..f3; compiler inserts the
        // counted vmcnt wait for exactly these loads).
        unsigned k[NSEG * 4];
        k[ 0]=key_of(f0.x); k[ 1]=key_of(f0.y); k[ 2]=key_of(f0.z); k[ 3]=key_of(f0.w);
        k[ 4]=key_of(f1.x); k[ 5]=key_of(f1.y); k[ 6]=key_of(f1.z); k[ 7]=key_of(f1.w);
        k[ 8]=key_of(f2.x); k[ 9]=key_of(f2.y); k[10]=key_of(f2.z); k[11]=key_of(f2.w);
        k[12]=key_of(f3.x); k[13]=key_of(f3.y); k[14]=key_of(f3.z); k[15]=key_of(f3.w);

        // ---- Prefetch next row NOW; stays in flight across the whole select.
        if (row + 1 < RPB) {
            const float4* pn = px + (long)(row + 1) * (D / 4);
            f0 = pn[tid]; f1 = pn[tid + TPB]; f2 = pn[tid + 2 * TPB]; f3 = pn[tid + 3 * TPB];
        }

        unsigned prefix = 0;   // decided high bits of threshold key
        unsigned rem = KKEEP;  // rank still to satisfy within current subset
        unsigned eqn = 0;      // count of keys == final threshold

        // ---- 3-round radix select, fields [31:21], [20:10], [9:0]
        #pragma unroll
        for (int r = 0; r < 3; ++r) {
            const int shift = (r == 0) ? 21 : (r == 1) ? 10 : 0;
            const unsigned mask = (r == 2) ? 1023u : 2047u;

            if (r == 0) {
                #pragma unroll
                for (int j = 0; j < 16; ++j)
                    atomicAdd(&hist[HA(k[j] >> 21)], 1u);
            } else {
                const int hs = (r == 1) ? 21 : 10;  // bits already decided
                #pragma unroll
                for (int j = 0; j < 16; ++j)
                    if ((k[j] >> hs) == (prefix >> hs))
                        atomicAdd(&hist[HA((k[j] >> shift) & mask)], 1u);
            }
            bar_lds();

            // Scan: thread t owns bins [8t,8t+8) at words 9t..9t+7 (9 coprime
            // to 32 -> conflict-free). Always re-zero for next round/next row.
            unsigned c[BPT];
            unsigned ct = 0;
            {
                const int hb = tid * 9;
                #pragma unroll
                for (int i = 0; i < BPT; ++i) { c[i] = hist[hb + i]; ct += c[i]; }
                #pragma unroll
                for (int i = 0; i < BPT; ++i) hist[hb + i] = 0;
            }
            unsigned s = ct;  // wave inclusive suffix scan of chunk totals
            #pragma unroll
            for (int off = 1; off < 64; off <<= 1) {
                unsigned t = __shfl_down(s, off, 64);
                if (lane + (unsigned)off < 64u) s += t;
            }
            if (lane == 0) s_wtot[wid] = s;
            bar_lds();
            unsigned above = s - ct;
            #pragma unroll
            for (unsigned w = 0; w < 4; ++w)
                if (w > wid) above += s_wtot[w];
            unsigned run = above;  // walk my 8 bins top-down; one crosses `rem`
            #pragma unroll
            for (int i = BPT - 1; i >= 0; --i) {
                unsigned incl = run + c[i];
                if (incl >= rem && run < rem) {
                    s_sel[0] = (unsigned)(tid * BPT + i);
                    s_sel[1] = rem - run;
                    s_sel[2] = c[i];
                }
                run = incl;
            }
            bar_lds();
            prefix |= s_sel[0] << shift;
            rem = s_sel[1];
            eqn = s_sel[2];
        }

        const unsigned tkey = prefix;
        float4* por = po + (long)row * (D / 4);

        // ---- Tie fast path: rem == eqn -> keep == (key >= tkey), no ranking.
        // Unique threshold (eqn=1=rem) in ~all rows of continuous random data.
        if (rem == eqn) {
            #pragma unroll
            for (int j = 0; j < NSEG; ++j) {
                float4 o;
                float* ofp = (float*)&o;
                #pragma unroll
                for (int c = 0; c < 4; ++c) {
                    const unsigned kk = k[4 * j + c];
                    ofp[c] = (kk >= tkey) ? val_of(kk) : 0.0f;
                }
                por[tid + j * TPB] = o;
            }
            continue;  // stores stay in flight under next row's select
        }

        // ---- Slow path (rare): tie-break rank in element-index order.
        unsigned e[NSEG];
        #pragma unroll
        for (int j = 0; j < NSEG; ++j) {
            unsigned c0 = (k[4*j+0] == tkey), c1 = (k[4*j+1] == tkey);
            unsigned c2 = (k[4*j+2] == tkey), c3 = (k[4*j+3] == tkey);
            e[j] = c0 + c1 + c2 + c3;
        }
        unsigned p01 = e[0] | (e[1] << 16);
        unsigned p23 = e[2] | (e[3] << 16);
        unsigned i01 = p01, i23 = p23;  // wave inclusive scans
        #pragma unroll
        for (int off = 1; off < 64; off <<= 1) {
            unsigned t0 = __shfl_up(i01, off, 64);
            unsigned t1 = __shfl_up(i23, off, 64);
            if (lane >= (unsigned)off) { i01 += t0; i23 += t1; }
        }
        if (lane == 63) { s_w01[wid] = i01; s_w23[wid] = i23; }
        bar_lds();
        unsigned x01 = i01 - p01, x23 = i23 - p23;  // exclusive within wave
        #pragma unroll
        for (unsigned w = 0; w < 4; ++w)
            if (w < wid) { x01 += s_w01[w]; x23 += s_w23[w]; }
        const unsigned tot01 = s_w01[0] + s_w01[1] + s_w01[2] + s_w01[3];
        const unsigned tot23 = s_w23[0] + s_w23[1] + s_w23[2] + s_w23[3];
        const unsigned total0 = tot01 & 0xffffu, total1 = tot01 >> 16;
        const unsigned total2 = tot23 & 0xffffu;
        unsigned rank[NSEG];
        rank[0] = (x01 & 0xffffu);
        rank[1] = total0 + (x01 >> 16);
        rank[2] = total0 + total1 + (x23 & 0xffffu);
        rank[3] = total0 + total1 + total2 + (x23 >> 16);
        // s_w01/s_w23 are re-read only in later slow-path rows, always after
        // another bar_lds; next fast-path rows never touch them.
        bar_lds();

        #pragma unroll
        for (int j = 0; j < NSEG; ++j) {
            float4 o;
            unsigned eqr = rank[j];
            float* ofp = (float*)&o;
            #pragma unroll
            for (int c = 0; c < 4; ++c) {
                const unsigned kk = k[4 * j + c];
                bool keep;
                if (kk > tkey)       keep = true;
                else if (kk == tkey) { keep = (eqr < rem); ++eqr; }
                else                 keep = false;
                ofp[c] = keep ? val_of(kk) : 0.0f;
            }
            por[tid + j * TPB] = o;
        }
    }
}

extern "C" void kernel_launch(void* const* d_in, const int* in_sizes, int n_in,
                              void* d_out, int out_size, void* d_ws, size_t ws_size,
                              hipStream_t stream) {
    const float* x = (const float*)d_in[0];
    float* out = (float*)d_out;
    const int rows = in_sizes[0] / D;        // 4*4096 = 16384
    const int blocks = rows / RPB;           // 2048 persistent blocks
    topk_keep_kernel<<<dim3(blocks), dim3(TPB), 0, stream>>>(x, out);
}

// Round 9
// 433.363 us; speedup vs baseline: 1.1959x; 1.1959x over previous
//
#include <hip/hip_runtime.h>

#define D     4096   // row length
#define KKEEP 512    // entries to keep per row
#define TPB   256    // threads per block (one block per row)
#define NSEG  4      // float4 segments per thread (D/4/TPB)
#define NB    2048   // histogram bins (11-bit digits; round 2 uses low 1024 only)
#define BPT   (NB / TPB)             // 8 bins per thread in the scan
#define HA(d) ((d) + ((d) >> 3))     // padded hist address: chunk base = 9*tid
#define HWORDS (NB + NB / 8)         // 2304 words

// Monotonic float -> uint key, 3 VALU ops (ashr, or, xor).
__device__ __forceinline__ unsigned key_of(float f) {
    unsigned u = __float_as_uint(f);
    return u ^ ((unsigned)((int)u >> 31) | 0x80000000u);
}

// One suffix-scan step within a 16-lane DPP row: lane i += lane (i+N), zero
// past the row end (bound_ctrl). row_shl:N = dpp_ctrl 0x100|N. This replaces
// a dependent ds_bpermute (~100+ cyc) with one VALU add (~4 cyc) -- the 6-deep
// bpermute chain per round was the longest dependent run in the kernel.
template<int N>
__device__ __forceinline__ unsigned sufstep(unsigned v) {
    int t = __builtin_amdgcn_update_dpp(0, (int)v, 0x100 | N, 0xf, 0xf, true);
    return v + (unsigned)t;
}

__global__ __launch_bounds__(TPB, 8)
void topk_keep_kernel(const float* __restrict__ x, float* __restrict__ out) {
    const int tid = threadIdx.x;
    const unsigned lane = tid & 63u, wid = (unsigned)tid >> 6;
    const unsigned row16 = lane >> 4;   // 16-lane DPP row index within wave
    const float4* px = (const float4*)(x + (long)blockIdx.x * D);
    float4*       po = (float4*)(out + (long)blockIdx.x * D);

    // ---- Coalesced load: thread t owns float4 indices {t + 256*j}.
    // Element index of (j, t, c) = j*1024 + 4t + c  -> (j,t,c) lex == index order.
    unsigned k[NSEG * 4];
    float    fv[NSEG * 4];
    {
        float4 f0 = px[tid], f1 = px[tid + TPB], f2 = px[tid + 2 * TPB], f3 = px[tid + 3 * TPB];
        fv[ 0]=f0.x; fv[ 1]=f0.y; fv[ 2]=f0.z; fv[ 3]=f0.w;
        fv[ 4]=f1.x; fv[ 5]=f1.y; fv[ 6]=f1.z; fv[ 7]=f1.w;
        fv[ 8]=f2.x; fv[ 9]=f2.y; fv[10]=f2.z; fv[11]=f2.w;
        fv[12]=f3.x; fv[13]=f3.y; fv[14]=f3.z; fv[15]=f3.w;
        #pragma unroll
        for (int j = 0; j < 16; ++j) k[j] = key_of(fv[j]);
    }

    __shared__ unsigned hist[HWORDS];
    __shared__ unsigned s_wtot[4];    // per-wave chunk totals (select scan)
    __shared__ unsigned s_sel[3];     // [selected digit, new remaining, bin count]
    __shared__ unsigned s_w01[4];     // tie slow path: packed seg0|seg1 totals
    __shared__ unsigned s_w23[4];     // tie slow path: packed seg2|seg3 totals

    // Zero once (incl. pad words 9t+8, never touched by atomics). Rounds 0/1
    // re-zero their bins in the scan read-out (fused, conflict-free 9-stride).
    #pragma unroll
    for (int i = 0; i < 9; ++i) hist[tid + i * TPB] = 0;
    __syncthreads();

    unsigned prefix = 0;   // decided high bits of threshold key (in place)
    unsigned rem = KKEEP;  // rank still to satisfy within current prefix subset
    unsigned eqn = 0;      // count of keys == prefix-subset selected bin

    // ---- 3-round radix select, fields [31:21], [20:10], [9:0] (MSB first).
    // Early exit when the selected bin's count == rem: then ALL bin members
    // are kept and keep == (key >= prefix) exactly, at any granularity. For
    // N(0,1) data the round-1 bin holds ~1.1 elems -> ~95% of rows skip r2.
    #pragma unroll
    for (int r = 0; r < 3; ++r) {
        const int shift = (r == 0) ? 21 : (r == 1) ? 10 : 0;
        const unsigned mask = (r == 2) ? 1023u : 2047u;

        if (r == 0) {
            #pragma unroll
            for (int j = 0; j < 16; ++j)
                atomicAdd(&hist[HA(k[j] >> 21)], 1u);
        } else {
            const int hs = (r == 1) ? 21 : 10;  // bits already decided
            #pragma unroll
            for (int j = 0; j < 16; ++j)
                if ((k[j] >> hs) == (prefix >> hs))
                    atomicAdd(&hist[HA((k[j] >> shift) & mask)], 1u);
        }
        __syncthreads();

        // Scan: thread t owns bins [8t,8t+8) at words 9t..9t+7 (9 coprime to
        // 32 -> conflict-free). Fused re-zero for the next round.
        unsigned c[BPT];
        unsigned ct = 0;
        {
            const int hb = tid * 9;
            #pragma unroll
            for (int i = 0; i < BPT; ++i) { c[i] = hist[hb + i]; ct += c[i]; }
            if (r < 2) {
                #pragma unroll
                for (int i = 0; i < BPT; ++i) hist[hb + i] = 0;
            }
        }
        // Wave inclusive SUFFIX scan of chunk totals:
        //  (a) 16-lane row suffix via 4 DPP adds (VALU-latency, not DS),
        //  (b) cross-row: 3 INDEPENDENT shfl broadcasts of row totals
        //      (lanes 16/32/48 hold row totals after (a)) -- one DS trip.
        unsigned s = ct;
        s = sufstep<1>(s); s = sufstep<2>(s); s = sufstep<4>(s); s = sufstep<8>(s);
        {
            unsigned T1 = __shfl(s, 16), T2 = __shfl(s, 32), T3 = __shfl(s, 48);
            s += (row16 < 1u ? T1 : 0u) + (row16 < 2u ? T2 : 0u) + (row16 < 3u ? T3 : 0u);
        }
        if (lane == 0) s_wtot[wid] = s;   // lane0 = wave total
        __syncthreads();
        unsigned above = s - ct;
        #pragma unroll
        for (unsigned w = 0; w < 4; ++w)
            if (w > wid) above += s_wtot[w];
        unsigned run = above;  // walk my 8 bins top-down; one bin crosses `rem`
        #pragma unroll
        for (int i = BPT - 1; i >= 0; --i) {
            unsigned incl = run + c[i];
            if (incl >= rem && run < rem) {
                s_sel[0] = (unsigned)(tid * BPT + i);
                s_sel[1] = rem - run;
                s_sel[2] = c[i];
            }
            run = incl;
        }
        __syncthreads();
        prefix |= s_sel[0] << shift;
        rem = s_sel[1];
        eqn = s_sel[2];
        if (rem == eqn) break;  // block-uniform (read from LDS after barrier)
    }

    // ---- Fast path: every key >= prefix is kept (covers early exit AND the
    // common full-3-round case with a unique threshold). 2 ops/elem emit.
    if (rem == eqn) {
        #pragma unroll
        for (int j = 0; j < NSEG; ++j) {
            float4 o;
            float* ofp = (float*)&o;
            #pragma unroll
            for (int c2 = 0; c2 < 4; ++c2) {
                const int idx = 4 * j + c2;
                ofp[c2] = (k[idx] >= prefix) ? fv[idx] : 0.0f;
            }
            po[tid + j * TPB] = o;
        }
        return;
    }

    // ---- Slow path (~1e-4 of rows): exact tie-break in element-index order.
    const unsigned tkey = prefix;
    unsigned e[NSEG];
    #pragma unroll
    for (int j = 0; j < NSEG; ++j) {
        unsigned c0 = (k[4*j+0] == tkey), c1 = (k[4*j+1] == tkey);
        unsigned c2 = (k[4*j+2] == tkey), c3 = (k[4*j+3] == tkey);
        e[j] = c0 + c1 + c2 + c3;
    }
    unsigned p01 = e[0] | (e[1] << 16);
    unsigned p23 = e[2] | (e[3] << 16);
    unsigned i01 = p01, i23 = p23;  // wave inclusive scans (sums <=1024/half)
    #pragma unroll
    for (int off = 1; off < 64; off <<= 1) {
        unsigned t0 = __shfl_up(i01, off, 64);
        unsigned t1 = __shfl_up(i23, off, 64);
        if (lane >= (unsigned)off) { i01 += t0; i23 += t1; }
    }
    if (lane == 63) { s_w01[wid] = i01; s_w23[wid] = i23; }
    __syncthreads();
    unsigned x01 = i01 - p01, x23 = i23 - p23;  // exclusive within wave
    #pragma unroll
    for (unsigned w = 0; w < 4; ++w)
        if (w < wid) { x01 += s_w01[w]; x23 += s_w23[w]; }
    const unsigned tot01 = s_w01[0] + s_w01[1] + s_w01[2] + s_w01[3];
    const unsigned tot23 = s_w23[0] + s_w23[1] + s_w23[2] + s_w23[3];
    const unsigned total0 = tot01 & 0xffffu, total1 = tot01 >> 16;
    const unsigned total2 = tot23 & 0xffffu;
    unsigned rank[NSEG];  // global equal-rank of my first equal in each segment
    rank[0] = (x01 & 0xffffu);
    rank[1] = total0 + (x01 >> 16);
    rank[2] = total0 + total1 + (x23 & 0xffffu);
    rank[3] = total0 + total1 + total2 + (x23 >> 16);

    #pragma unroll
    for (int j = 0; j < NSEG; ++j) {
        float4 o;
        unsigned eqr = rank[j];
        float* ofp = (float*)&o;
        #pragma unroll
        for (int c2 = 0; c2 < 4; ++c2) {
            const int idx = 4 * j + c2;
            const unsigned kk = k[idx];
            bool keep;
            if (kk > tkey)       keep = true;
            else if (kk == tkey) { keep = (eqr < rem); ++eqr; }
            else                 keep = false;
            ofp[c2] = keep ? fv[idx] : 0.0f;
        }
        po[tid + j * TPB] = o;
    }
}

extern "C" void kernel_launch(void* const* d_in, const int* in_sizes, int n_in,
                              void* d_out, int out_size, void* d_ws, size_t ws_size,
                              hipStream_t stream) {
    const float* x = (const float*)d_in[0];
    float* out = (float*)d_out;
    const int rows = in_sizes[0] / D;  // 4*4096 = 16384
    topk_keep_kernel<<<dim3(rows), dim3(TPB), 0, stream>>>(x, out);
}